// Round 10
// baseline (1328.389 us; speedup 1.0000x reference)
//
#include <hip/hip_runtime.h>
#include <math.h>

typedef _Float16 h8 __attribute__((ext_vector_type(8)));
typedef float f4 __attribute__((ext_vector_type(4)));

// ---------------------------------------------------------------------------
// Workspace layout (float element offsets). Peak ~141 MB.
// All activations NHWC f16 (channel-last, channels padded to mult of 8).
// Scale chain: sims stored x2^-10 (f16 range), r1 dsc=1024; regressor
// activations stored x1/64, consumers dsc=64; k_final un-scales x64. All pow2.
// ---------------------------------------------------------------------------
static const size_t OFF_SIMSH = 256;        // sims NHWC f16 (6,2304,8) = 55296 fl
static const size_t OFF_WB    = 56000;      // weight banks f16
static const size_t ARENA     = 3503808;
// phase 1 (backbone + features)
static const size_t IMH    = ARENA;                 // (2,147456,8) h
static const size_t B1H    = IMH + 1179648;         // (2,36864,64) h
static const size_t B2H    = B1H + 2359296;         // (2,9216,256) h
static const size_t F3H    = B2H + 2359296;         // (2,2304,512) h
static const size_t F4H    = F3H + 1179648;         // (2,576,1024) h
static const size_t PRAW   = F4H + 589824;          // fp32, 2359296
static const size_t PSC    = PRAW + 2359296;        // fp32, 8957952
static const size_t SIMRAW = PSC + 8957952;         // fp32, 51840
static const size_t WSIM   = SIMRAW + 51840;        // f16 bank, 15925248 h
// phase 2 (regressor) reuses arena
static const size_t R1H = ARENA;                    // (6,2304,200) h
static const size_t U1H = R1H + 1382400;            // (6,9216,200) h
static const size_t R2H = U1H + 5529600;            // (6,9216,128) h
static const size_t U2H = R2H + 3538944;            // (6,36864,128) h
static const size_t R3H = U2H + 14155776;           // (6,36864,64) h

// f16-unit offsets inside WB bank
static const size_t WB1 = 0;          // 52kq x 64
static const size_t WB2 = 26624;      // 72 x 256
static const size_t WB3 = 174080;     // 288 x 512
static const size_t WB4 = 1353728;    // 576 x 1024
static const size_t WR1 = 6072320;    // 52 x 256
static const size_t WR2 = 6178816;    // 628 x 128
static const size_t WR3 = 6821888;    // 144 x 64

// ---------------------------------------------------------------------------
__global__ __launch_bounds__(64) void k_meta(const float* __restrict__ tlbrs,
                                             int* __restrict__ meta)
{
    if (threadIdx.x != 0 || blockIdx.x != 0) return;
    const double SC[3] = {1.0, 0.9, 1.1};
    for (int b = 0; b < 2; ++b)
        for (int lvl = 0; lvl < 2; ++lvl) {
            int FH = lvl ? 24 : 48;
            float scaling = lvl ? 16.f : 8.f;
            int base = (b * 2 + lvl) * 32;
            int PH = 0, PW = 0;
            for (int p = 0; p < 3; ++p) {
                const float* t4 = tlbrs + (b * 3 + p) * 4;
                float st = t4[0] / scaling, sl = t4[1] / scaling;
                float sb = t4[2] / scaling, sr = t4[3] / scaling;
                int top  = (int)fmaxf(floorf(st), 0.f);
                int left = (int)fmaxf(floorf(sl), 0.f);
                int bot  = (int)fminf(ceilf(sb) + 1.f, (float)FH);
                int rgt  = (int)fminf(ceilf(sr) + 1.f, (float)FH);
                meta[base + p * 4 + 0] = top;
                meta[base + p * 4 + 1] = left;
                meta[base + p * 4 + 2] = bot;
                meta[base + p * 4 + 3] = rgt;
                PH = max(PH, bot - top);
                PW = max(PW, rgt - left);
            }
            meta[base + 12] = PH;
            meta[base + 13] = PW;
            for (int s = 0; s < 3; ++s) {
                int PHs = (int)ceil((double)PH * SC[s]);
                int PWs = (int)ceil((double)PW * SC[s]);
                if (PHs < 1) PHs = PH;
                if (PWs < 1) PWs = PW;
                meta[base + 14 + s * 2] = PHs;
                meta[base + 15 + s * 2] = PWs;
            }
        }
}

// ---------------------------------------------------------------------------
__global__ __launch_bounds__(256) void k_im2hwc(const float* __restrict__ img,
    _Float16* __restrict__ o)
{
    int idx = blockIdx.x * 256 + threadIdx.x;
    if (idx >= 2359296) return;
    int c = idx & 7;
    int pix = (idx >> 3) % 147456;
    int b = (idx >> 3) / 147456;
    float v = (c < 3) ? img[((size_t)b * 3 + c) * 147456 + pix] : 0.f;
    o[idx] = (_Float16)v;
}

// ---------------------------------------------------------------------------
__global__ __launch_bounds__(256) void k_wprepH(const float* __restrict__ w,
    _Float16* __restrict__ wB, int Cin, int KKt, int Cinp, int Cout, int Coutp,
    int total)
{
    int idx = blockIdx.x * 256 + threadIdx.x;
    if (idx >= total) return;
    int j = idx & 7;
    int co = (idx >> 3) % Coutp;
    int kq = idx / (8 * Coutp);
    int k = kq * 8 + j;
    int tap = k / Cinp, cip = k - tap * Cinp;
    float v = 0.f;
    if (tap < KKt && cip < Cin && co < Cout)
        v = w[((size_t)co * Cin + cip) * KKt + tap];
    wB[idx] = (_Float16)v;
}

// ---------------------------------------------------------------------------
// LDS-free NHWC implicit-GEMM conv, f16 MFMA 16x16x32, fp32 accum.
// BM=128 px, BN=64 co, BK=32; 4 waves = (wr, wc) each 64x32.
// A/B fragments direct global->VGPR; SOFTWARE-PIPELINED depth 1 (double-
// buffered fragments, load k+1 overlaps MFMA k). Pixel base pointers hoisted.
// Epilogue: relu(acc*dsc+bias)*osc -> f16 NHWC (co>=Cout -> 0).
// ---------------------------------------------------------------------------
template<int KK, int KW, int S, int CINP>
__global__ __launch_bounds__(256) void k_convH(
    const _Float16* __restrict__ in, const _Float16* __restrict__ wB,
    const float* __restrict__ bias, _Float16* __restrict__ out,
    int Hin, int Win, int Cout, int Coutp, int Hout, int Wout,
    int pad, int Kpad, int storeC, float dsc, float osc)
{
    const int tid = threadIdx.x;
    const int M = Hout * Wout;
    const int n_img = blockIdx.z;
    const int m0 = blockIdx.x * 128;
    const int co0 = blockIdx.y * 64;
    const _Float16* inb = in + (size_t)n_img * Hin * Win * CINP;

    const int wv = tid >> 6, lane = tid & 63;
    const int wr = wv & 1, wc = wv >> 1;
    const int lq = lane >> 4, lr = lane & 15;

    int ybase[4], xbase[4];
    bool mval[4];
    const _Float16* pb[4];
#pragma unroll
    for (int mt = 0; mt < 4; ++mt) {
        int m = m0 + wr * 64 + mt * 16 + lr;
        mval[mt] = m < M;
        int y = m / Wout, x = m % Wout;
        ybase[mt] = y * S - pad;
        xbase[mt] = x * S - pad;
        pb[mt] = inb + ((long)ybase[mt] * Win + xbase[mt]) * CINP;
    }
    const _Float16* wbc = wB + (size_t)(co0 + wc * 32 + lr) * 8;

    f4 acc[4][2];
#pragma unroll
    for (int i = 0; i < 4; ++i)
#pragma unroll
        for (int j = 0; j < 2; ++j) { f4 z = {0.f, 0.f, 0.f, 0.f}; acc[i][j] = z; }

    const int Ksteps = Kpad >> 5;

    auto load_step = [&](int kb, h8* afX, h8* bfX) {
        int k0 = kb * 32 + lq * 8;
        int tap = k0 / CINP;              // CINP multiple of 8 -> no straddle
        int ci0 = k0 - tap * CINP;
        int dy = tap / KW, dx = tap - dy * KW;
        bool tval = tap < KK;
        size_t kq = (size_t)(kb * 4 + lq) * Coutp;
#pragma unroll
        for (int nt = 0; nt < 2; ++nt)
            bfX[nt] = *(const h8*)(wbc + (kq + nt * 16) * 8);
        int doff = (dy * Win + dx) * CINP + ci0;
#pragma unroll
        for (int mt = 0; mt < 4; ++mt) {
            int gy = ybase[mt] + dy, gx = xbase[mt] + dx;
            bool ok = mval[mt] && tval &&
                      (unsigned)gy < (unsigned)Hin && (unsigned)gx < (unsigned)Win;
            if (ok) {
                afX[mt] = *(const h8*)(pb[mt] + doff);
            } else {
#pragma unroll
                for (int j = 0; j < 8; ++j) afX[mt][j] = (_Float16)0.f;
            }
        }
    };
    auto mfma_step = [&](h8* afX, h8* bfX) {
#pragma unroll
        for (int mt = 0; mt < 4; ++mt)
#pragma unroll
            for (int nt = 0; nt < 2; ++nt)
                acc[mt][nt] = __builtin_amdgcn_mfma_f32_16x16x32_f16(
                    afX[mt], bfX[nt], acc[mt][nt], 0, 0, 0);
    };

    h8 afA[4], bfA[2], afB[4], bfB[2];
    load_step(0, afA, bfA);
    int kb = 0;
    for (; kb + 1 < Ksteps; kb += 2) {
        load_step(kb + 1, afB, bfB);
        mfma_step(afA, bfA);
        if (kb + 2 < Ksteps) load_step(kb + 2, afA, bfA);
        mfma_step(afB, bfB);
    }
    if (kb < Ksteps) mfma_step(afA, bfA);

    _Float16* ob = out + (size_t)n_img * M * storeC;
#pragma unroll
    for (int nt = 0; nt < 2; ++nt) {
        int co = co0 + wc * 32 + nt * 16 + lr;
        if (co >= storeC) continue;
        bool valid = co < Cout;
        float bv = (bias && valid) ? bias[co] : 0.f;
#pragma unroll
        for (int mt = 0; mt < 4; ++mt) {
#pragma unroll
            for (int reg = 0; reg < 4; ++reg) {
                int m = m0 + wr * 64 + mt * 16 + lq * 4 + reg;
                if (m < M) {
                    float v = valid
                        ? fmaxf(fmaf(acc[mt][nt][reg], dsc, bv), 0.f) * osc : 0.f;
                    ob[(size_t)m * storeC + co] = (_Float16)v;
                }
            }
        }
    }
}

// ---------------------------------------------------------------------------
__global__ __launch_bounds__(256) void k_praw(const _Float16* __restrict__ f3h,
    const _Float16* __restrict__ f4h, const int* __restrict__ meta,
    float* __restrict__ praw)
{
    int z = blockIdx.z;
    int p = z % 3, m = z / 3, lvl = m % 2, b = m / 2;
    int c = blockIdx.y;
    int FC = lvl ? 1024 : 512;
    if (c >= FC) return;
    int FH = lvl ? 24 : 48;
    int fsh = lvl ? 10 : 9;
    const int* mb = meta + m * 32;
    int PH = mb[12], PW = mb[13];
    int oy = threadIdx.x / 16, ox = threadIdx.x % 16;
    if (oy >= PH || ox >= PW) return;
    int top = mb[p * 4 + 0], left = mb[p * 4 + 1];
    int bot = mb[p * 4 + 2], rgt = mb[p * 4 + 3];
    int h = bot - top, w = rgt - left;
    const _Float16* fm = lvl ? (f4h + (size_t)b * 589824)
                             : (f3h + (size_t)b * 1179648);
    float sy = ((oy + 0.5f) * h) / PH - 0.5f;
    sy = fminf(fmaxf(sy, 0.f), (float)(h - 1));
    int y0 = (int)floorf(sy); float ty = sy - y0; int y1 = min(y0 + 1, h - 1);
    float sx = ((ox + 0.5f) * w) / PW - 0.5f;
    sx = fminf(fmaxf(sx, 0.f), (float)(w - 1));
    int x0 = (int)floorf(sx); float tx = sx - x0; int x1 = min(x0 + 1, w - 1);
    float v00 = (float)fm[((size_t)((top + y0) * FH + (left + x0)) << fsh) + c];
    float v01 = (float)fm[((size_t)((top + y0) * FH + (left + x1)) << fsh) + c];
    float v10 = (float)fm[((size_t)((top + y1) * FH + (left + x0)) << fsh) + c];
    float v11 = (float)fm[((size_t)((top + y1) * FH + (left + x1)) << fsh) + c];
    float v = (1.f - ty) * ((1.f - tx) * v00 + tx * v01)
            +        ty  * ((1.f - tx) * v10 + tx * v11);
    size_t base = (size_t)(b * 1179648 + (lvl ? 393216 : 0)) + ((size_t)p * FC + c) * 256;
    praw[base + oy * 16 + ox] = v;
}

// ---------------------------------------------------------------------------
__global__ __launch_bounds__(256) void k_psc(const float* __restrict__ praw,
    const int* __restrict__ meta, float* __restrict__ psc)
{
    int z = blockIdx.z;
    int p = z % 3, s = (z / 3) % 3, lvl = (z / 9) % 2, b = z / 18;
    int c = blockIdx.y;
    int FC = lvl ? 1024 : 512;
    if (c >= FC) return;
    const int* mb = meta + (b * 2 + lvl) * 32;
    int PH = mb[12], PW = mb[13];
    int PHs = mb[14 + s * 2], PWs = mb[15 + s * 2];
    int idx = blockIdx.x * 256 + threadIdx.x;
    int ys = idx / 18, xs = idx % 18;
    if (ys >= PHs || xs >= PWs) return;
    const float* src = praw + (size_t)(b * 1179648 + (lvl ? 393216 : 0))
                            + ((size_t)p * FC + c) * 256;
    float sy = ((ys + 0.5f) * PH) / PHs - 0.5f;
    sy = fminf(fmaxf(sy, 0.f), (float)(PH - 1));
    int y0 = (int)floorf(sy); float ty = sy - y0; int y1 = min(y0 + 1, PH - 1);
    float sx = ((xs + 0.5f) * PW) / PWs - 0.5f;
    sx = fminf(fmaxf(sx, 0.f), (float)(PW - 1));
    int x0 = (int)floorf(sx); float tx = sx - x0; int x1 = min(x0 + 1, PW - 1);
    float v = (1.f - ty) * ((1.f - tx) * src[y0 * 16 + x0] + tx * src[y0 * 16 + x1])
            +        ty  * ((1.f - tx) * src[y1 * 16 + x0] + tx * src[y1 * 16 + x1]);
    size_t base = (size_t)b * 4478976 + (lvl ? (1492992 + (size_t)s * 995328)
                                             : ((size_t)s * 497664));
    psc[base + ((size_t)p * FC + c) * 324 + ys * 18 + xs] = v;
}

__global__ __launch_bounds__(256) void k_fill0(float* p, int n)
{
    int i = blockIdx.x * 256 + threadIdx.x;
    if (i < n) p[i] = 0.f;
}

// ---------------------------------------------------------------------------
// Sim filter bank, k = tap*FC + c ordering: Wz[kq][n(16)][8] f16.
// ---------------------------------------------------------------------------
__global__ __launch_bounds__(256) void k_wsim(const float* __restrict__ psc,
    const int* __restrict__ meta, _Float16* __restrict__ W)
{
    int z = blockIdx.z;                 // b*2+lvl
    int lvl = z & 1, b = z >> 1;
    int FC = lvl ? 1024 : 512;
    int fsh = lvl ? 10 : 9;
    int total = FC * 324 * 16;
    int e = blockIdx.x * 256 + threadIdx.x;
    if (e >= total) return;
    _Float16* Wz = W + (size_t)b * 7962624 + (lvl ? 2654208 : 0);
    int j = e & 7, n = (e >> 3) & 15, kq = e >> 7;
    int k = kq * 8 + j;
    int tap = k >> fsh, c = k & (FC - 1);
    int rr = tap / 18, cc = tap - rr * 18;
    float v = 0.f;
    if (n < 9) {
        int s = n / 3, p = n % 3;
        const int* mb = meta + z * 32;
        int PHs = mb[14 + s * 2], PWs = mb[15 + s * 2];
        int ky = rr - (9 - (PHs >> 1));
        int kx = cc - (9 - (PWs >> 1));
        if ((unsigned)ky < (unsigned)PHs && (unsigned)kx < (unsigned)PWs) {
            size_t base = (size_t)b * 4478976 + (lvl ? (1492992 + (size_t)s * 995328)
                                                     : ((size_t)s * 497664));
            v = psc[base + ((size_t)p * FC + c) * 324 + ky * 18 + kx];
        }
    }
    Wz[e] = (_Float16)v;
}

// ---------------------------------------------------------------------------
// Sim GEMM, LDS-free, software-pipelined. Grid (mg, kchunk, b). Wave owns TW
// 16-px m-subtiles looped inside the K-loop. Split-K via fp32 atomicAdd.
// ---------------------------------------------------------------------------
template<int TW, int FH, int FSH, bool LVL>
__global__ __launch_bounds__(256) void k_simL(
    const _Float16* __restrict__ f, const _Float16* __restrict__ W,
    float* __restrict__ simraw, int Kc)
{
    const int M = FH * FH;
    const int b = blockIdx.z;
    const int mg = blockIdx.x;
    const int kstart = blockIdx.y * Kc;
    const _Float16* fm = f + (size_t)b * ((size_t)M << FSH);
    const _Float16* Wz = W + (size_t)b * 7962624;
    const int tid = threadIdx.x;
    const int wv = tid >> 6, lane = tid & 63;
    const int lq = lane >> 4, lr = lane & 15;

    int ybase[TW], xbase[TW];
    const _Float16* pb[TW];
#pragma unroll
    for (int i = 0; i < TW; ++i) {
        int st = mg * (4 * TW) + wv + 4 * i;
        int m = st * 16 + lr;
        ybase[i] = m / FH - 9;
        xbase[i] = m % FH - 9;
        pb[i] = fm + (((long)ybase[i] * FH + xbase[i]) << FSH);
    }
    f4 acc[TW];
#pragma unroll
    for (int i = 0; i < TW; ++i) { f4 z = {0.f, 0.f, 0.f, 0.f}; acc[i] = z; }

    auto load_step = [&](int ks, h8* avX, h8& bfX) {
        int k0 = ks * 32;
        int tap = k0 >> FSH;                       // uniform (scalar)
        int c0 = (k0 & ((1 << FSH) - 1)) + lq * 8;
        int dy = tap / 18, dx = tap - dy * 18;
        bfX = *(const h8*)(Wz + ((size_t)((k0 >> 3) + lq) * 16 + lr) * 8);
        long doff = ((long)(dy * FH + dx) << FSH) + c0;
#pragma unroll
        for (int i = 0; i < TW; ++i) {
            int gy = ybase[i] + dy, gx = xbase[i] + dx;
            if ((unsigned)gy < (unsigned)FH && (unsigned)gx < (unsigned)FH) {
                avX[i] = *(const h8*)(pb[i] + doff);
            } else {
#pragma unroll
                for (int j = 0; j < 8; ++j) avX[i][j] = (_Float16)0.f;
            }
        }
    };
    auto mfma_step = [&](h8* avX, h8 bfX) {
#pragma unroll
        for (int i = 0; i < TW; ++i)
            acc[i] = __builtin_amdgcn_mfma_f32_16x16x32_f16(avX[i], bfX, acc[i], 0, 0, 0);
    };

    h8 avA[TW], avB[TW], bfA, bfB;
    load_step(kstart, avA, bfA);
    int kb = 0;
    for (; kb + 1 < Kc; kb += 2) {
        load_step(kstart + kb + 1, avB, bfB);
        mfma_step(avA, bfA);
        if (kb + 2 < Kc) load_step(kstart + kb + 2, avA, bfA);
        mfma_step(avB, bfB);
    }
    if (kb < Kc) mfma_step(avA, bfA);

    if (lr < 9) {
        int s = lr / 3, p = lr - s * 3;
        float* base = simraw + (size_t)b * 25920
                    + (LVL ? (20736 + (size_t)s * 1728) : ((size_t)s * 6912))
                    + (size_t)p * M;
#pragma unroll
        for (int i = 0; i < TW; ++i) {
            int st = mg * (4 * TW) + wv + 4 * i;
            int row0 = st * 16 + lq * 4;
#pragma unroll
            for (int r = 0; r < 4; ++r) {
                int m = row0 + r;
                if (m < M) atomicAdd(base + m, acc[i][r]);
            }
        }
    }
}

// ---------------------------------------------------------------------------
// Assemble sims -> NHWC f16, stored x 2^-10 (range safety; r1 dsc=1024)
// ---------------------------------------------------------------------------
__global__ __launch_bounds__(256) void k_sims(const float* __restrict__ simraw,
    _Float16* __restrict__ simsh)
{
    int idx = blockIdx.x * 256 + threadIdx.x;
    if (idx >= 110592) return;
    int scat = idx & 7;
    int rest = idx >> 3;
    int x = rest % 48, y = (rest / 48) % 48;
    int p = (rest / 2304) % 3, b = rest / 6912;
    float v = 0.f;
    if (scat < 6) {
        int lvl = scat / 3, s = scat % 3;
        if (lvl == 0) {
            v = simraw[(size_t)b * 25920 + (size_t)s * 6912 + (size_t)p * 2304 + y * 48 + x];
        } else {
            const float* src = simraw + (size_t)b * 25920 + 20736 + (size_t)s * 1728
                                      + (size_t)p * 576;
            float sy = (y + 0.5f) * 0.5f - 0.5f; sy = fminf(fmaxf(sy, 0.f), 23.f);
            int y0 = (int)floorf(sy); float ty = sy - y0; int y1 = min(y0 + 1, 23);
            float sx = (x + 0.5f) * 0.5f - 0.5f; sx = fminf(fmaxf(sx, 0.f), 23.f);
            int x0 = (int)floorf(sx); float tx = sx - x0; int x1 = min(x0 + 1, 23);
            v = (1.f - ty) * ((1.f - tx) * src[y0 * 24 + x0] + tx * src[y0 * 24 + x1])
              +        ty  * ((1.f - tx) * src[y1 * 24 + x0] + tx * src[y1 * 24 + x1]);
        }
    }
    simsh[idx] = (_Float16)(v * 0.0009765625f);   // x 2^-10
}

// ---------------------------------------------------------------------------
__global__ __launch_bounds__(256) void k_up2acH(const h8* __restrict__ in,
    h8* __restrict__ out, int N_, int Hin, int Win, int Cg)
{
    int Hout = 2 * Hin, Wout = 2 * Win;
    size_t total = (size_t)N_ * Hout * Wout * Cg;
    size_t idx = (size_t)blockIdx.x * 256 + threadIdx.x;
    if (idx >= total) return;
    int cg = (int)(idx % Cg);
    size_t r = idx / Cg;
    int x = (int)(r % Wout);
    int y = (int)((r / Wout) % Hout);
    int n = (int)(r / ((size_t)Wout * Hout));
    int dh = 2 * Hin - 1, dw = 2 * Win - 1;
    int ay = y * (Hin - 1);
    int y0 = ay / dh; int y1 = min(y0 + 1, Hin - 1);
    float ty = (float)(ay - y0 * dh) / (float)dh;
    int ax = x * (Win - 1);
    int x0 = ax / dw; int x1 = min(x0 + 1, Win - 1);
    float tx = (float)(ax - x0 * dw) / (float)dw;
    const h8* base = in + (size_t)n * Hin * Win * Cg;
    h8 a = base[((size_t)y0 * Win + x0) * Cg + cg];
    h8 b8 = base[((size_t)y0 * Win + x1) * Cg + cg];
    h8 c8 = base[((size_t)y1 * Win + x0) * Cg + cg];
    h8 d8 = base[((size_t)y1 * Win + x1) * Cg + cg];
    float w00 = (1.f - ty) * (1.f - tx), w01 = (1.f - ty) * tx;
    float w10 = ty * (1.f - tx), w11 = ty * tx;
    h8 o;
#pragma unroll
    for (int j = 0; j < 8; ++j)
        o[j] = (_Float16)(w00 * (float)a[j] + w01 * (float)b8[j]
                        + w10 * (float)c8[j] + w11 * (float)d8[j]);
    out[idx] = o;
}

// ---------------------------------------------------------------------------
__global__ __launch_bounds__(256) void k_final(const h8* __restrict__ r3h,
    const float* __restrict__ w4, const float* __restrict__ b4,
    const float* __restrict__ w5, const float* __restrict__ b5,
    float* __restrict__ out)
{
    __shared__ float sw4[2048];
    __shared__ float sb4[32];
    __shared__ float sw5[32];
    int tid = threadIdx.x;
    for (int i = tid; i < 2048; i += 256) sw4[i] = w4[i];
    if (tid < 32) { sb4[tid] = b4[tid]; sw5[tid] = w5[tid]; }
    __syncthreads();
    int idx = blockIdx.x * 256 + tid;
    int x = idx % 384, y = (idx / 384) % 384, b = idx / 147456;
    int ay = y * 191; int y0 = ay / 383; int y1 = min(y0 + 1, 191);
    float ty = (float)(ay - y0 * 383) / 383.f;
    int ax = x * 191; int x0 = ax / 383; int x1 = min(x0 + 1, 191);
    float tx = (float)(ax - x0 * 383) / 383.f;
    float w00 = (1.f - ty) * (1.f - tx), w01 = (1.f - ty) * tx;
    float w10 = ty * (1.f - tx), w11 = ty * tx;
    float best = 0.f;
    for (int p = 0; p < 3; ++p) {
        int n = b * 3 + p;
        float acc[32];
#pragma unroll
        for (int co = 0; co < 32; ++co) acc[co] = sb4[co];
        const h8* rb = r3h + (size_t)n * 36864 * 8;
        for (int cg = 0; cg < 8; ++cg) {
            h8 a00 = rb[(size_t)(y0 * 192 + x0) * 8 + cg];
            h8 a01 = rb[(size_t)(y0 * 192 + x1) * 8 + cg];
            h8 a10 = rb[(size_t)(y1 * 192 + x0) * 8 + cg];
            h8 a11 = rb[(size_t)(y1 * 192 + x1) * 8 + cg];
#pragma unroll
            for (int jj = 0; jj < 8; ++jj) {
                float v = (w00 * (float)a00[jj] + w01 * (float)a01[jj]
                         + w10 * (float)a10[jj] + w11 * (float)a11[jj]) * 64.f;
                int ci = cg * 8 + jj;
#pragma unroll
                for (int co = 0; co < 32; ++co)
                    acc[co] = fmaf(sw4[co * 64 + ci], v, acc[co]);
            }
        }
        float s5 = b5[0];
#pragma unroll
        for (int co = 0; co < 32; ++co)
            s5 = fmaf(fmaxf(acc[co], 0.f), sw5[co], s5);
        s5 = fmaxf(s5, 0.f);
        best = fmaxf(best, s5);
    }
    out[idx] = best;
}

// ---------------------------------------------------------------------------
extern "C" void kernel_launch(void* const* d_in, const int* in_sizes, int n_in,
                              void* d_out, int out_size, void* d_ws, size_t ws_size,
                              hipStream_t stream)
{
    (void)in_sizes; (void)n_in; (void)out_size; (void)ws_size;
    const float* images = (const float*)d_in[0];
    const float* tlbrs  = (const float*)d_in[1];
    const float* fw1 = (const float*)d_in[2];
    const float* fw2 = (const float*)d_in[3];
    const float* fw3 = (const float*)d_in[4];
    const float* fw4 = (const float*)d_in[5];
    const float* rw1 = (const float*)d_in[6];
    const float* rb1 = (const float*)d_in[7];
    const float* rw2 = (const float*)d_in[8];
    const float* rb2 = (const float*)d_in[9];
    const float* rw3 = (const float*)d_in[10];
    const float* rb3 = (const float*)d_in[11];
    const float* rw4 = (const float*)d_in[12];
    const float* rb4 = (const float*)d_in[13];
    const float* rw5 = (const float*)d_in[14];
    const float* rb5 = (const float*)d_in[15];
    float* wsf = (float*)d_ws;
    int* meta = (int*)d_ws;
    float* out = (float*)d_out;
    _Float16* wb    = (_Float16*)(wsf + OFF_WB);
    _Float16* simsh = (_Float16*)(wsf + OFF_SIMSH);
    _Float16* imh   = (_Float16*)(wsf + IMH);
    _Float16* b1h   = (_Float16*)(wsf + B1H);
    _Float16* b2h   = (_Float16*)(wsf + B2H);
    _Float16* f3h   = (_Float16*)(wsf + F3H);
    _Float16* f4h   = (_Float16*)(wsf + F4H);
    _Float16* wsim  = (_Float16*)(wsf + WSIM);
    _Float16* r1h   = (_Float16*)(wsf + R1H);
    _Float16* u1h   = (_Float16*)(wsf + U1H);
    _Float16* r2h   = (_Float16*)(wsf + R2H);
    _Float16* u2h   = (_Float16*)(wsf + U2H);
    _Float16* r3h   = (_Float16*)(wsf + R3H);

    const float INV64 = 1.f / 64.f;

    hipLaunchKernelGGL(k_meta, dim3(1), dim3(64), 0, stream, tlbrs, meta);
    hipLaunchKernelGGL(k_im2hwc, dim3(9216), dim3(256), 0, stream, images, imh);

    // ---- weight banks ----
    hipLaunchKernelGGL(k_wprepH, dim3(104), dim3(256), 0, stream,
        fw1, wb + WB1, 3, 49, 8, 64, 64, 26624);
    hipLaunchKernelGGL(k_wprepH, dim3(576), dim3(256), 0, stream,
        fw2, wb + WB2, 64, 9, 64, 256, 256, 147456);
    hipLaunchKernelGGL(k_wprepH, dim3(4608), dim3(256), 0, stream,
        fw3, wb + WB3, 256, 9, 256, 512, 512, 1179648);
    hipLaunchKernelGGL(k_wprepH, dim3(18432), dim3(256), 0, stream,
        fw4, wb + WB4, 512, 9, 512, 1024, 1024, 4718592);
    hipLaunchKernelGGL(k_wprepH, dim3(416), dim3(256), 0, stream,
        rw1, wb + WR1, 6, 49, 8, 196, 256, 106496);
    hipLaunchKernelGGL(k_wprepH, dim3(2512), dim3(256), 0, stream,
        rw2, wb + WR2, 196, 25, 200, 128, 128, 643072);
    hipLaunchKernelGGL(k_wprepH, dim3(288), dim3(256), 0, stream,
        rw3, wb + WR3, 128, 9, 128, 64, 64, 73728);

    // ---- backbone (NHWC f16) ----
    hipLaunchKernelGGL((k_convH<49, 7, 2, 8>), dim3(288, 1, 2), dim3(256), 0, stream,
        imh, wb + WB1, (const float*)nullptr, b1h,
        384, 384, 64, 64, 192, 192, 3, 416, 64, 1.f, 1.f);
    hipLaunchKernelGGL((k_convH<9, 3, 2, 64>), dim3(72, 4, 2), dim3(256), 0, stream,
        b1h, wb + WB2, (const float*)nullptr, b2h,
        192, 192, 256, 256, 96, 96, 1, 576, 256, 1.f, 1.f);
    hipLaunchKernelGGL((k_convH<9, 3, 2, 256>), dim3(18, 8, 2), dim3(256), 0, stream,
        b2h, wb + WB3, (const float*)nullptr, f3h,
        96, 96, 512, 512, 48, 48, 1, 2304, 512, 1.f, 1.f);
    hipLaunchKernelGGL((k_convH<9, 3, 2, 512>), dim3(5, 16, 2), dim3(256), 0, stream,
        f3h, wb + WB4, (const float*)nullptr, f4h,
        48, 48, 1024, 1024, 24, 24, 1, 4608, 1024, 1.f, 1.f);

    // ---- feature extraction ----
    hipLaunchKernelGGL(k_praw, dim3(1, 1024, 12), dim3(256), 0, stream,
        f3h, f4h, meta, wsf + PRAW);
    hipLaunchKernelGGL(k_psc, dim3(2, 1024, 36), dim3(256), 0, stream,
        wsf + PRAW, meta, wsf + PSC);
    hipLaunchKernelGGL(k_wsim, dim3(20736, 1, 4), dim3(256), 0, stream,
        wsf + PSC, meta, wsim);
    hipLaunchKernelGGL(k_fill0, dim3(203), dim3(256), 0, stream,
        wsf + SIMRAW, 51840);
    // lvl0: 6 m-groups x 96 K-chunks (Kc=54)  -> 1152 blocks
    hipLaunchKernelGGL((k_simL<6, 48, 9, false>), dim3(6, 96, 2), dim3(256), 0, stream,
        f3h, wsim, wsf + SIMRAW, 54);
    // lvl1: 3 m-groups x 144 K-chunks (Kc=72) -> 864 blocks
    hipLaunchKernelGGL((k_simL<3, 24, 10, true>), dim3(3, 144, 2), dim3(256), 0, stream,
        f4h, wsim + 2654208, wsf + SIMRAW, 72);
    hipLaunchKernelGGL(k_sims, dim3(432), dim3(256), 0, stream,
        wsf + SIMRAW, simsh);

    // ---- count regressor (NHWC f16; sims scaled 2^-10 -> r1 dsc=1024) ----
    hipLaunchKernelGGL((k_convH<49, 7, 1, 8>), dim3(18, 4, 6), dim3(256), 0, stream,
        simsh, wb + WR1, rb1, r1h,
        48, 48, 196, 256, 48, 48, 3, 416, 200, 1024.f, INV64);
    hipLaunchKernelGGL(k_up2acH, dim3(5400), dim3(256), 0, stream,
        (const h8*)r1h, (h8*)u1h, 6, 48, 48, 25);
    hipLaunchKernelGGL((k_convH<25, 5, 1, 200>), dim3(72, 2, 6), dim3(256), 0, stream,
        u1h, wb + WR2, rb2, r2h,
        96, 96, 128, 128, 96, 96, 2, 5024, 128, 64.f, INV64);
    hipLaunchKernelGGL(k_up2acH, dim3(13824), dim3(256), 0, stream,
        (const h8*)r2h, (h8*)u2h, 6, 96, 96, 16);
    hipLaunchKernelGGL((k_convH<9, 3, 1, 128>), dim3(288, 1, 6), dim3(256), 0, stream,
        u2h, wb + WR3, rb3, r3h,
        192, 192, 64, 64, 192, 192, 1, 1152, 64, 64.f, INV64);
    hipLaunchKernelGGL(k_final, dim3(1152), dim3(256), 0, stream,
        (const h8*)r3h, rw4, rb4, rw5, rb5, out);
}

// Round 11
// 1283.492 us; speedup vs baseline: 1.0350x; 1.0350x over previous
//
#include <hip/hip_runtime.h>
#include <math.h>

typedef _Float16 h8 __attribute__((ext_vector_type(8)));
typedef float f4 __attribute__((ext_vector_type(4)));

// ---------------------------------------------------------------------------
// Workspace layout (float element offsets). Peak ~141 MB.
// All activations NHWC f16 (channel-last, channels padded to mult of 8).
// Scale chain: sims stored x2^-10 (f16 range), r1 dsc=1024; regressor
// activations stored x1/64, consumers dsc=64; k_final un-scales x64. All pow2.
// ---------------------------------------------------------------------------
static const size_t OFF_SIMSH = 256;        // sims NHWC f16 (6,2304,8) = 55296 fl
static const size_t OFF_WB    = 56000;      // weight banks f16
static const size_t ARENA     = 3503808;
// phase 1 (backbone + features)
static const size_t IMH    = ARENA;                 // (2,147456,8) h
static const size_t B1H    = IMH + 1179648;         // (2,36864,64) h
static const size_t B2H    = B1H + 2359296;         // (2,9216,256) h
static const size_t F3H    = B2H + 2359296;         // (2,2304,512) h
static const size_t F4H    = F3H + 1179648;         // (2,576,1024) h
static const size_t PRAW   = F4H + 589824;          // fp32, 2359296
static const size_t PSC    = PRAW + 2359296;        // fp32, 8957952
static const size_t SIMRAW = PSC + 8957952;         // fp32, 51840
static const size_t WSIM   = SIMRAW + 51840;        // f16 bank, 15925248 h
// phase 2 (regressor) reuses arena
static const size_t R1H = ARENA;                    // (6,2304,200) h
static const size_t U1H = R1H + 1382400;            // (6,9216,200) h
static const size_t R2H = U1H + 5529600;            // (6,9216,128) h
static const size_t U2H = R2H + 3538944;            // (6,36864,128) h
static const size_t R3H = U2H + 14155776;           // (6,36864,64) h

// f16-unit offsets inside WB bank
static const size_t WB1 = 0;          // 52kq x 64
static const size_t WB2 = 26624;      // 72 x 256
static const size_t WB3 = 174080;    // 288 x 512
static const size_t WB4 = 1353728;   // 576 x 1024
static const size_t WR1 = 6072320;   // 52 x 256
static const size_t WR2 = 6178816;   // 628 x 128
static const size_t WR3 = 6821888;   // 144 x 64

// ---------------------------------------------------------------------------
__global__ __launch_bounds__(64) void k_meta(const float* __restrict__ tlbrs,
                                             int* __restrict__ meta)
{
    if (threadIdx.x != 0 || blockIdx.x != 0) return;
    const double SC[3] = {1.0, 0.9, 1.1};
    for (int b = 0; b < 2; ++b)
        for (int lvl = 0; lvl < 2; ++lvl) {
            int FH = lvl ? 24 : 48;
            float scaling = lvl ? 16.f : 8.f;
            int base = (b * 2 + lvl) * 32;
            int PH = 0, PW = 0;
            for (int p = 0; p < 3; ++p) {
                const float* t4 = tlbrs + (b * 3 + p) * 4;
                float st = t4[0] / scaling, sl = t4[1] / scaling;
                float sb = t4[2] / scaling, sr = t4[3] / scaling;
                int top  = (int)fmaxf(floorf(st), 0.f);
                int left = (int)fmaxf(floorf(sl), 0.f);
                int bot  = (int)fminf(ceilf(sb) + 1.f, (float)FH);
                int rgt  = (int)fminf(ceilf(sr) + 1.f, (float)FH);
                meta[base + p * 4 + 0] = top;
                meta[base + p * 4 + 1] = left;
                meta[base + p * 4 + 2] = bot;
                meta[base + p * 4 + 3] = rgt;
                PH = max(PH, bot - top);
                PW = max(PW, rgt - left);
            }
            meta[base + 12] = PH;
            meta[base + 13] = PW;
            for (int s = 0; s < 3; ++s) {
                int PHs = (int)ceil((double)PH * SC[s]);
                int PWs = (int)ceil((double)PW * SC[s]);
                if (PHs < 1) PHs = PH;
                if (PWs < 1) PWs = PW;
                meta[base + 14 + s * 2] = PHs;
                meta[base + 15 + s * 2] = PWs;
            }
        }
}

// ---------------------------------------------------------------------------
__global__ __launch_bounds__(256) void k_im2hwc(const float* __restrict__ img,
    _Float16* __restrict__ o)
{
    int idx = blockIdx.x * 256 + threadIdx.x;
    if (idx >= 2359296) return;
    int c = idx & 7;
    int pix = (idx >> 3) % 147456;
    int b = (idx >> 3) / 147456;
    float v = (c < 3) ? img[((size_t)b * 3 + c) * 147456 + pix] : 0.f;
    o[idx] = (_Float16)v;
}

// ---------------------------------------------------------------------------
__global__ __launch_bounds__(256) void k_wprepH(const float* __restrict__ w,
    _Float16* __restrict__ wB, int Cin, int KKt, int Cinp, int Cout, int Coutp,
    int total)
{
    int idx = blockIdx.x * 256 + threadIdx.x;
    if (idx >= total) return;
    int j = idx & 7;
    int co = (idx >> 3) % Coutp;
    int kq = idx / (8 * Coutp);
    int k = kq * 8 + j;
    int tap = k / Cinp, cip = k - tap * Cinp;
    float v = 0.f;
    if (tap < KKt && cip < Cin && co < Cout)
        v = w[((size_t)co * Cin + cip) * KKt + tap];
    wB[idx] = (_Float16)v;
}

// ---------------------------------------------------------------------------
// LDS-free NHWC implicit-GEMM conv, f16 MFMA 16x16x32, fp32 accum.
// BM = MT*32 px, BN=64 co, BK=32; 4 waves = (wr, wc) each (MT*16)x32.
// MT=2 doubles block count for latency-bound low-grid layers.
// A/B fragments direct global->VGPR; software-pipelined depth 1.
// Epilogue: relu(acc*dsc+bias)*osc -> f16 NHWC (co>=Cout -> 0).
// ---------------------------------------------------------------------------
template<int KK, int KW, int S, int CINP, int MT>
__global__ __launch_bounds__(256) void k_convH(
    const _Float16* __restrict__ in, const _Float16* __restrict__ wB,
    const float* __restrict__ bias, _Float16* __restrict__ out,
    int Hin, int Win, int Cout, int Coutp, int Hout, int Wout,
    int pad, int Kpad, int storeC, float dsc, float osc)
{
    const int tid = threadIdx.x;
    const int M = Hout * Wout;
    const int n_img = blockIdx.z;
    const int m0 = blockIdx.x * (MT * 32);
    const int co0 = blockIdx.y * 64;
    const _Float16* inb = in + (size_t)n_img * Hin * Win * CINP;

    const int wv = tid >> 6, lane = tid & 63;
    const int wr = wv & 1, wc = wv >> 1;
    const int lq = lane >> 4, lr = lane & 15;

    int ybase[MT], xbase[MT];
    bool mval[MT];
    const _Float16* pb[MT];
#pragma unroll
    for (int mt = 0; mt < MT; ++mt) {
        int m = m0 + (wr * MT + mt) * 16 + lr;
        mval[mt] = m < M;
        int y = m / Wout, x = m % Wout;
        ybase[mt] = y * S - pad;
        xbase[mt] = x * S - pad;
        pb[mt] = inb + ((long)ybase[mt] * Win + xbase[mt]) * CINP;
    }
    const _Float16* wbc = wB + (size_t)(co0 + wc * 32 + lr) * 8;

    f4 acc[MT][2];
#pragma unroll
    for (int i = 0; i < MT; ++i)
#pragma unroll
        for (int j = 0; j < 2; ++j) { f4 z = {0.f, 0.f, 0.f, 0.f}; acc[i][j] = z; }

    const int Ksteps = Kpad >> 5;

    auto load_step = [&](int kb, h8* afX, h8* bfX) {
        int k0 = kb * 32 + lq * 8;
        int tap = k0 / CINP;              // CINP multiple of 8 -> no straddle
        int ci0 = k0 - tap * CINP;
        int dy = tap / KW, dx = tap - dy * KW;
        bool tval = tap < KK;
        size_t kq = (size_t)(kb * 4 + lq) * Coutp;
#pragma unroll
        for (int nt = 0; nt < 2; ++nt)
            bfX[nt] = *(const h8*)(wbc + (kq + nt * 16) * 8);
        int doff = (dy * Win + dx) * CINP + ci0;
#pragma unroll
        for (int mt = 0; mt < MT; ++mt) {
            int gy = ybase[mt] + dy, gx = xbase[mt] + dx;
            bool ok = mval[mt] && tval &&
                      (unsigned)gy < (unsigned)Hin && (unsigned)gx < (unsigned)Win;
            if (ok) {
                afX[mt] = *(const h8*)(pb[mt] + doff);
            } else {
#pragma unroll
                for (int j = 0; j < 8; ++j) afX[mt][j] = (_Float16)0.f;
            }
        }
    };
    auto mfma_step = [&](h8* afX, h8* bfX) {
#pragma unroll
        for (int mt = 0; mt < MT; ++mt)
#pragma unroll
            for (int nt = 0; nt < 2; ++nt)
                acc[mt][nt] = __builtin_amdgcn_mfma_f32_16x16x32_f16(
                    afX[mt], bfX[nt], acc[mt][nt], 0, 0, 0);
    };

    h8 afA[MT], bfA[2], afB[MT], bfB[2];
    load_step(0, afA, bfA);
    int kb = 0;
    for (; kb + 1 < Ksteps; kb += 2) {
        load_step(kb + 1, afB, bfB);
        mfma_step(afA, bfA);
        if (kb + 2 < Ksteps) load_step(kb + 2, afA, bfA);
        mfma_step(afB, bfB);
    }
    if (kb < Ksteps) mfma_step(afA, bfA);

    _Float16* ob = out + (size_t)n_img * M * storeC;
#pragma unroll
    for (int nt = 0; nt < 2; ++nt) {
        int co = co0 + wc * 32 + nt * 16 + lr;
        if (co >= storeC) continue;
        bool valid = co < Cout;
        float bv = (bias && valid) ? bias[co] : 0.f;
#pragma unroll
        for (int mt = 0; mt < MT; ++mt) {
#pragma unroll
            for (int reg = 0; reg < 4; ++reg) {
                int m = m0 + (wr * MT + mt) * 16 + lq * 4 + reg;
                if (m < M) {
                    float v = valid
                        ? fmaxf(fmaf(acc[mt][nt][reg], dsc, bv), 0.f) * osc : 0.f;
                    ob[(size_t)m * storeC + co] = (_Float16)v;
                }
            }
        }
    }
}

// ---------------------------------------------------------------------------
__global__ __launch_bounds__(256) void k_praw(const _Float16* __restrict__ f3h,
    const _Float16* __restrict__ f4h, const int* __restrict__ meta,
    float* __restrict__ praw)
{
    int z = blockIdx.z;
    int p = z % 3, m = z / 3, lvl = m % 2, b = m / 2;
    int c = blockIdx.y;
    int FC = lvl ? 1024 : 512;
    if (c >= FC) return;
    int FH = lvl ? 24 : 48;
    int fsh = lvl ? 10 : 9;
    const int* mb = meta + m * 32;
    int PH = mb[12], PW = mb[13];
    int oy = threadIdx.x / 16, ox = threadIdx.x % 16;
    if (oy >= PH || ox >= PW) return;
    int top = mb[p * 4 + 0], left = mb[p * 4 + 1];
    int bot = mb[p * 4 + 2], rgt = mb[p * 4 + 3];
    int h = bot - top, w = rgt - left;
    const _Float16* fm = lvl ? (f4h + (size_t)b * 589824)
                             : (f3h + (size_t)b * 1179648);
    float sy = ((oy + 0.5f) * h) / PH - 0.5f;
    sy = fminf(fmaxf(sy, 0.f), (float)(h - 1));
    int y0 = (int)floorf(sy); float ty = sy - y0; int y1 = min(y0 + 1, h - 1);
    float sx = ((ox + 0.5f) * w) / PW - 0.5f;
    sx = fminf(fmaxf(sx, 0.f), (float)(w - 1));
    int x0 = (int)floorf(sx); float tx = sx - x0; int x1 = min(x0 + 1, w - 1);
    float v00 = (float)fm[((size_t)((top + y0) * FH + (left + x0)) << fsh) + c];
    float v01 = (float)fm[((size_t)((top + y0) * FH + (left + x1)) << fsh) + c];
    float v10 = (float)fm[((size_t)((top + y1) * FH + (left + x0)) << fsh) + c];
    float v11 = (float)fm[((size_t)((top + y1) * FH + (left + x1)) << fsh) + c];
    float v = (1.f - ty) * ((1.f - tx) * v00 + tx * v01)
            +        ty  * ((1.f - tx) * v10 + tx * v11);
    size_t base = (size_t)(b * 1179648 + (lvl ? 393216 : 0)) + ((size_t)p * FC + c) * 256;
    praw[base + oy * 16 + ox] = v;
}

// ---------------------------------------------------------------------------
__global__ __launch_bounds__(256) void k_psc(const float* __restrict__ praw,
    const int* __restrict__ meta, float* __restrict__ psc)
{
    int z = blockIdx.z;
    int p = z % 3, s = (z / 3) % 3, lvl = (z / 9) % 2, b = z / 18;
    int c = blockIdx.y;
    int FC = lvl ? 1024 : 512;
    if (c >= FC) return;
    const int* mb = meta + (b * 2 + lvl) * 32;
    int PH = mb[12], PW = mb[13];
    int PHs = mb[14 + s * 2], PWs = mb[15 + s * 2];
    int idx = blockIdx.x * 256 + threadIdx.x;
    int ys = idx / 18, xs = idx % 18;
    if (ys >= PHs || xs >= PWs) return;
    const float* src = praw + (size_t)(b * 1179648 + (lvl ? 393216 : 0))
                            + ((size_t)p * FC + c) * 256;
    float sy = ((ys + 0.5f) * PH) / PHs - 0.5f;
    sy = fminf(fmaxf(sy, 0.f), (float)(PH - 1));
    int y0 = (int)floorf(sy); float ty = sy - y0; int y1 = min(y0 + 1, PH - 1);
    float sx = ((xs + 0.5f) * PW) / PWs - 0.5f;
    sx = fminf(fmaxf(sx, 0.f), (float)(PW - 1));
    int x0 = (int)floorf(sx); float tx = sx - x0; int x1 = min(x0 + 1, PW - 1);
    float v = (1.f - ty) * ((1.f - tx) * src[y0 * 16 + x0] + tx * src[y0 * 16 + x1])
            +        ty  * ((1.f - tx) * src[y1 * 16 + x0] + tx * src[y1 * 16 + x1]);
    size_t base = (size_t)b * 4478976 + (lvl ? (1492992 + (size_t)s * 995328)
                                             : ((size_t)s * 497664));
    psc[base + ((size_t)p * FC + c) * 324 + ys * 18 + xs] = v;
}

__global__ __launch_bounds__(256) void k_fill0(float* p, int n)
{
    int i = blockIdx.x * 256 + threadIdx.x;
    if (i < n) p[i] = 0.f;
}

// ---------------------------------------------------------------------------
// Sim filter bank, k = tap*FC + c ordering: Wz[kq][n(16)][8] f16.
// ---------------------------------------------------------------------------
__global__ __launch_bounds__(256) void k_wsim(const float* __restrict__ psc,
    const int* __restrict__ meta, _Float16* __restrict__ W)
{
    int z = blockIdx.z;                 // b*2+lvl
    int lvl = z & 1, b = z >> 1;
    int FC = lvl ? 1024 : 512;
    int fsh = lvl ? 10 : 9;
    int total = FC * 324 * 16;
    int e = blockIdx.x * 256 + threadIdx.x;
    if (e >= total) return;
    _Float16* Wz = W + (size_t)b * 7962624 + (lvl ? 2654208 : 0);
    int j = e & 7, n = (e >> 3) & 15, kq = e >> 7;
    int k = kq * 8 + j;
    int tap = k >> fsh, c = k & (FC - 1);
    int rr = tap / 18, cc = tap - rr * 18;
    float v = 0.f;
    if (n < 9) {
        int s = n / 3, p = n % 3;
        const int* mb = meta + z * 32;
        int PHs = mb[14 + s * 2], PWs = mb[15 + s * 2];
        int ky = rr - (9 - (PHs >> 1));
        int kx = cc - (9 - (PWs >> 1));
        if ((unsigned)ky < (unsigned)PHs && (unsigned)kx < (unsigned)PWs) {
            size_t base = (size_t)b * 4478976 + (lvl ? (1492992 + (size_t)s * 995328)
                                                     : ((size_t)s * 497664));
            v = psc[base + ((size_t)p * FC + c) * 324 + ky * 18 + kx];
        }
    }
    Wz[e] = (_Float16)v;
}

// ---------------------------------------------------------------------------
// Sim GEMM, LDS-free, software-pipelined. Grid (mg, kchunk, b). Wave owns TW
// 16-px m-subtiles looped inside the K-loop. Split-K via fp32 atomicAdd.
// ---------------------------------------------------------------------------
template<int TW, int FH, int FSH, bool LVL>
__global__ __launch_bounds__(256) void k_simL(
    const _Float16* __restrict__ f, const _Float16* __restrict__ W,
    float* __restrict__ simraw, int Kc)
{
    const int M = FH * FH;
    const int b = blockIdx.z;
    const int mg = blockIdx.x;
    const int kstart = blockIdx.y * Kc;
    const _Float16* fm = f + (size_t)b * ((size_t)M << FSH);
    const _Float16* Wz = W + (size_t)b * 7962624;
    const int tid = threadIdx.x;
    const int wv = tid >> 6, lane = tid & 63;
    const int lq = lane >> 4, lr = lane & 15;

    int ybase[TW], xbase[TW];
    const _Float16* pb[TW];
#pragma unroll
    for (int i = 0; i < TW; ++i) {
        int st = mg * (4 * TW) + wv + 4 * i;
        int m = st * 16 + lr;
        ybase[i] = m / FH - 9;
        xbase[i] = m % FH - 9;
        pb[i] = fm + (((long)ybase[i] * FH + xbase[i]) << FSH);
    }
    f4 acc[TW];
#pragma unroll
    for (int i = 0; i < TW; ++i) { f4 z = {0.f, 0.f, 0.f, 0.f}; acc[i] = z; }

    auto load_step = [&](int ks, h8* avX, h8& bfX) {
        int k0 = ks * 32;
        int tap = k0 >> FSH;                       // uniform (scalar)
        int c0 = (k0 & ((1 << FSH) - 1)) + lq * 8;
        int dy = tap / 18, dx = tap - dy * 18;
        bfX = *(const h8*)(Wz + ((size_t)((k0 >> 3) + lq) * 16 + lr) * 8);
        long doff = ((long)(dy * FH + dx) << FSH) + c0;
#pragma unroll
        for (int i = 0; i < TW; ++i) {
            int gy = ybase[i] + dy, gx = xbase[i] + dx;
            if ((unsigned)gy < (unsigned)FH && (unsigned)gx < (unsigned)FH) {
                avX[i] = *(const h8*)(pb[i] + doff);
            } else {
#pragma unroll
                for (int j = 0; j < 8; ++j) avX[i][j] = (_Float16)0.f;
            }
        }
    };
    auto mfma_step = [&](h8* avX, h8 bfX) {
#pragma unroll
        for (int i = 0; i < TW; ++i)
            acc[i] = __builtin_amdgcn_mfma_f32_16x16x32_f16(avX[i], bfX, acc[i], 0, 0, 0);
    };

    h8 avA[TW], avB[TW], bfA, bfB;
    load_step(kstart, avA, bfA);
    int kb = 0;
    for (; kb + 1 < Kc; kb += 2) {
        load_step(kstart + kb + 1, avB, bfB);
        mfma_step(avA, bfA);
        if (kb + 2 < Kc) load_step(kstart + kb + 2, avA, bfA);
        mfma_step(avB, bfB);
    }
    if (kb < Kc) mfma_step(avA, bfA);

    if (lr < 9) {
        int s = lr / 3, p = lr - s * 3;
        float* base = simraw + (size_t)b * 25920
                    + (LVL ? (20736 + (size_t)s * 1728) : ((size_t)s * 6912))
                    + (size_t)p * M;
#pragma unroll
        for (int i = 0; i < TW; ++i) {
            int st = mg * (4 * TW) + wv + 4 * i;
            int row0 = st * 16 + lq * 4;
#pragma unroll
            for (int r = 0; r < 4; ++r) {
                int m = row0 + r;
                if (m < M) atomicAdd(base + m, acc[i][r]);
            }
        }
    }
}

// ---------------------------------------------------------------------------
// Assemble sims -> NHWC f16, stored x 2^-10 (range safety; r1 dsc=1024)
// ---------------------------------------------------------------------------
__global__ __launch_bounds__(256) void k_sims(const float* __restrict__ simraw,
    _Float16* __restrict__ simsh)
{
    int idx = blockIdx.x * 256 + threadIdx.x;
    if (idx >= 110592) return;
    int scat = idx & 7;
    int rest = idx >> 3;
    int x = rest % 48, y = (rest / 48) % 48;
    int p = (rest / 2304) % 3, b = rest / 6912;
    float v = 0.f;
    if (scat < 6) {
        int lvl = scat / 3, s = scat % 3;
        if (lvl == 0) {
            v = simraw[(size_t)b * 25920 + (size_t)s * 6912 + (size_t)p * 2304 + y * 48 + x];
        } else {
            const float* src = simraw + (size_t)b * 25920 + 20736 + (size_t)s * 1728
                                      + (size_t)p * 576;
            float sy = (y + 0.5f) * 0.5f - 0.5f; sy = fminf(fmaxf(sy, 0.f), 23.f);
            int y0 = (int)floorf(sy); float ty = sy - y0; int y1 = min(y0 + 1, 23);
            float sx = (x + 0.5f) * 0.5f - 0.5f; sx = fminf(fmaxf(sx, 0.f), 23.f);
            int x0 = (int)floorf(sx); float tx = sx - x0; int x1 = min(x0 + 1, 23);
            v = (1.f - ty) * ((1.f - tx) * src[y0 * 24 + x0] + tx * src[y0 * 24 + x1])
              +        ty  * ((1.f - tx) * src[y1 * 24 + x0] + tx * src[y1 * 24 + x1]);
        }
    }
    simsh[idx] = (_Float16)(v * 0.0009765625f);   // x 2^-10
}

// ---------------------------------------------------------------------------
__global__ __launch_bounds__(256) void k_up2acH(const h8* __restrict__ in,
    h8* __restrict__ out, int N_, int Hin, int Win, int Cg)
{
    int Hout = 2 * Hin, Wout = 2 * Win;
    size_t total = (size_t)N_ * Hout * Wout * Cg;
    size_t idx = (size_t)blockIdx.x * 256 + threadIdx.x;
    if (idx >= total) return;
    int cg = (int)(idx % Cg);
    size_t r = idx / Cg;
    int x = (int)(r % Wout);
    int y = (int)((r / Wout) % Hout);
    int n = (int)(r / ((size_t)Wout * Hout));
    int dh = 2 * Hin - 1, dw = 2 * Win - 1;
    int ay = y * (Hin - 1);
    int y0 = ay / dh; int y1 = min(y0 + 1, Hin - 1);
    float ty = (float)(ay - y0 * dh) / (float)dh;
    int ax = x * (Win - 1);
    int x0 = ax / dw; int x1 = min(x0 + 1, Win - 1);
    float tx = (float)(ax - x0 * dw) / (float)dw;
    const h8* base = in + (size_t)n * Hin * Win * Cg;
    h8 a = base[((size_t)y0 * Win + x0) * Cg + cg];
    h8 b8 = base[((size_t)y0 * Win + x1) * Cg + cg];
    h8 c8 = base[((size_t)y1 * Win + x0) * Cg + cg];
    h8 d8 = base[((size_t)y1 * Win + x1) * Cg + cg];
    float w00 = (1.f - ty) * (1.f - tx), w01 = (1.f - ty) * tx;
    float w10 = ty * (1.f - tx), w11 = ty * tx;
    h8 o;
#pragma unroll
    for (int j = 0; j < 8; ++j)
        o[j] = (_Float16)(w00 * (float)a[j] + w01 * (float)b8[j]
                        + w10 * (float)c8[j] + w11 * (float)d8[j]);
    out[idx] = o;
}

// ---------------------------------------------------------------------------
__global__ __launch_bounds__(256) void k_final(const h8* __restrict__ r3h,
    const float* __restrict__ w4, const float* __restrict__ b4,
    const float* __restrict__ w5, const float* __restrict__ b5,
    float* __restrict__ out)
{
    __shared__ float sw4[2048];
    __shared__ float sb4[32];
    __shared__ float sw5[32];
    int tid = threadIdx.x;
    for (int i = tid; i < 2048; i += 256) sw4[i] = w4[i];
    if (tid < 32) { sb4[tid] = b4[tid]; sw5[tid] = w5[tid]; }
    __syncthreads();
    int idx = blockIdx.x * 256 + tid;
    int x = idx % 384, y = (idx / 384) % 384, b = idx / 147456;
    int ay = y * 191; int y0 = ay / 383; int y1 = min(y0 + 1, 191);
    float ty = (float)(ay - y0 * 383) / 383.f;
    int ax = x * 191; int x0 = ax / 383; int x1 = min(x0 + 1, 191);
    float tx = (float)(ax - x0 * 383) / 383.f;
    float w00 = (1.f - ty) * (1.f - tx), w01 = (1.f - ty) * tx;
    float w10 = ty * (1.f - tx), w11 = ty * tx;
    float best = 0.f;
    for (int p = 0; p < 3; ++p) {
        int n = b * 3 + p;
        float acc[32];
#pragma unroll
        for (int co = 0; co < 32; ++co) acc[co] = sb4[co];
        const h8* rb = r3h + (size_t)n * 36864 * 8;
        for (int cg = 0; cg < 8; ++cg) {
            h8 a00 = rb[(size_t)(y0 * 192 + x0) * 8 + cg];
            h8 a01 = rb[(size_t)(y0 * 192 + x1) * 8 + cg];
            h8 a10 = rb[(size_t)(y1 * 192 + x0) * 8 + cg];
            h8 a11 = rb[(size_t)(y1 * 192 + x1) * 8 + cg];
#pragma unroll
            for (int jj = 0; jj < 8; ++jj) {
                float v = (w00 * (float)a00[jj] + w01 * (float)a01[jj]
                         + w10 * (float)a10[jj] + w11 * (float)a11[jj]) * 64.f;
                int ci = cg * 8 + jj;
#pragma unroll
                for (int co = 0; co < 32; ++co)
                    acc[co] = fmaf(sw4[co * 64 + ci], v, acc[co]);
            }
        }
        float s5 = b5[0];
#pragma unroll
        for (int co = 0; co < 32; ++co)
            s5 = fmaf(fmaxf(acc[co], 0.f), sw5[co], s5);
        s5 = fmaxf(s5, 0.f);
        best = fmaxf(best, s5);
    }
    out[idx] = best;
}

// ---------------------------------------------------------------------------
extern "C" void kernel_launch(void* const* d_in, const int* in_sizes, int n_in,
                              void* d_out, int out_size, void* d_ws, size_t ws_size,
                              hipStream_t stream)
{
    (void)in_sizes; (void)n_in; (void)out_size; (void)ws_size;
    const float* images = (const float*)d_in[0];
    const float* tlbrs  = (const float*)d_in[1];
    const float* fw1 = (const float*)d_in[2];
    const float* fw2 = (const float*)d_in[3];
    const float* fw3 = (const float*)d_in[4];
    const float* fw4 = (const float*)d_in[5];
    const float* rw1 = (const float*)d_in[6];
    const float* rb1 = (const float*)d_in[7];
    const float* rw2 = (const float*)d_in[8];
    const float* rb2 = (const float*)d_in[9];
    const float* rw3 = (const float*)d_in[10];
    const float* rb3 = (const float*)d_in[11];
    const float* rw4 = (const float*)d_in[12];
    const float* rb4 = (const float*)d_in[13];
    const float* rw5 = (const float*)d_in[14];
    const float* rb5 = (const float*)d_in[15];
    float* wsf = (float*)d_ws;
    int* meta = (int*)d_ws;
    float* out = (float*)d_out;
    _Float16* wb    = (_Float16*)(wsf + OFF_WB);
    _Float16* simsh = (_Float16*)(wsf + OFF_SIMSH);
    _Float16* imh   = (_Float16*)(wsf + IMH);
    _Float16* b1h   = (_Float16*)(wsf + B1H);
    _Float16* b2h   = (_Float16*)(wsf + B2H);
    _Float16* f3h   = (_Float16*)(wsf + F3H);
    _Float16* f4h   = (_Float16*)(wsf + F4H);
    _Float16* wsim  = (_Float16*)(wsf + WSIM);
    _Float16* r1h   = (_Float16*)(wsf + R1H);
    _Float16* u1h   = (_Float16*)(wsf + U1H);
    _Float16* r2h   = (_Float16*)(wsf + R2H);
    _Float16* u2h   = (_Float16*)(wsf + U2H);
    _Float16* r3h   = (_Float16*)(wsf + R3H);

    const float INV64 = 1.f / 64.f;

    hipLaunchKernelGGL(k_meta, dim3(1), dim3(64), 0, stream, tlbrs, meta);
    hipLaunchKernelGGL(k_im2hwc, dim3(9216), dim3(256), 0, stream, images, imh);

    // ---- weight banks ----
    hipLaunchKernelGGL(k_wprepH, dim3(104), dim3(256), 0, stream,
        fw1, wb + WB1, 3, 49, 8, 64, 64, 26624);
    hipLaunchKernelGGL(k_wprepH, dim3(576), dim3(256), 0, stream,
        fw2, wb + WB2, 64, 9, 64, 256, 256, 147456);
    hipLaunchKernelGGL(k_wprepH, dim3(4608), dim3(256), 0, stream,
        fw3, wb + WB3, 256, 9, 256, 512, 512, 1179648);
    hipLaunchKernelGGL(k_wprepH, dim3(18432), dim3(256), 0, stream,
        fw4, wb + WB4, 512, 9, 512, 1024, 1024, 4718592);
    hipLaunchKernelGGL(k_wprepH, dim3(416), dim3(256), 0, stream,
        rw1, wb + WR1, 6, 49, 8, 196, 256, 106496);
    hipLaunchKernelGGL(k_wprepH, dim3(2512), dim3(256), 0, stream,
        rw2, wb + WR2, 196, 25, 200, 128, 128, 643072);
    hipLaunchKernelGGL(k_wprepH, dim3(288), dim3(256), 0, stream,
        rw3, wb + WR3, 128, 9, 128, 64, 64, 73728);

    // ---- backbone (NHWC f16; MT=2 -> BM=64 for grid-limited layers) ----
    hipLaunchKernelGGL((k_convH<49, 7, 2, 8, 2>), dim3(576, 1, 2), dim3(256), 0, stream,
        imh, wb + WB1, (const float*)nullptr, b1h,
        384, 384, 64, 64, 192, 192, 3, 416, 64, 1.f, 1.f);
    hipLaunchKernelGGL((k_convH<9, 3, 2, 64, 2>), dim3(144, 4, 2), dim3(256), 0, stream,
        b1h, wb + WB2, (const float*)nullptr, b2h,
        192, 192, 256, 256, 96, 96, 1, 576, 256, 1.f, 1.f);
    hipLaunchKernelGGL((k_convH<9, 3, 2, 256, 2>), dim3(36, 8, 2), dim3(256), 0, stream,
        b2h, wb + WB3, (const float*)nullptr, f3h,
        96, 96, 512, 512, 48, 48, 1, 2304, 512, 1.f, 1.f);
    hipLaunchKernelGGL((k_convH<9, 3, 2, 512, 2>), dim3(9, 16, 2), dim3(256), 0, stream,
        f3h, wb + WB4, (const float*)nullptr, f4h,
        48, 48, 1024, 1024, 24, 24, 1, 4608, 1024, 1.f, 1.f);

    // ---- feature extraction ----
    hipLaunchKernelGGL(k_praw, dim3(1, 1024, 12), dim3(256), 0, stream,
        f3h, f4h, meta, wsf + PRAW);
    hipLaunchKernelGGL(k_psc, dim3(2, 1024, 36), dim3(256), 0, stream,
        wsf + PRAW, meta, wsf + PSC);
    hipLaunchKernelGGL(k_wsim, dim3(20736, 1, 4), dim3(256), 0, stream,
        wsf + PSC, meta, wsim);
    hipLaunchKernelGGL(k_fill0, dim3(203), dim3(256), 0, stream,
        wsf + SIMRAW, 51840);
    // lvl0: 6 m-groups x 96 K-chunks (Kc=54)  -> 1152 blocks
    hipLaunchKernelGGL((k_simL<6, 48, 9, false>), dim3(6, 96, 2), dim3(256), 0, stream,
        f3h, wsim, wsf + SIMRAW, 54);
    // lvl1: 3 m-groups x 144 K-chunks (Kc=72) -> 864 blocks
    hipLaunchKernelGGL((k_simL<3, 24, 10, true>), dim3(3, 144, 2), dim3(256), 0, stream,
        f4h, wsim + 2654208, wsf + SIMRAW, 72);
    hipLaunchKernelGGL(k_sims, dim3(432), dim3(256), 0, stream,
        wsf + SIMRAW, simsh);

    // ---- count regressor (NHWC f16; sims scaled 2^-10 -> r1 dsc=1024) ----
    hipLaunchKernelGGL((k_convH<49, 7, 1, 8, 2>), dim3(36, 4, 6), dim3(256), 0, stream,
        simsh, wb + WR1, rb1, r1h,
        48, 48, 196, 256, 48, 48, 3, 416, 200, 1024.f, INV64);
    hipLaunchKernelGGL(k_up2acH, dim3(5400), dim3(256), 0, stream,
        (const h8*)r1h, (h8*)u1h, 6, 48, 48, 25);
    hipLaunchKernelGGL((k_convH<25, 5, 1, 200, 2>), dim3(144, 2, 6), dim3(256), 0, stream,
        u1h, wb + WR2, rb2, r2h,
        96, 96, 128, 128, 96, 96, 2, 5024, 128, 64.f, INV64);
    hipLaunchKernelGGL(k_up2acH, dim3(13824), dim3(256), 0, stream,
        (const h8*)r2h, (h8*)u2h, 6, 96, 96, 16);
    hipLaunchKernelGGL((k_convH<9, 3, 1, 128, 4>), dim3(288, 1, 6), dim3(256), 0, stream,
        u2h, wb + WR3, rb3, r3h,
        192, 192, 64, 64, 192, 192, 1, 1152, 64, 64.f, INV64);
    hipLaunchKernelGGL(k_final, dim3(1152), dim3(256), 0, stream,
        (const h8*)r3h, rw4, rb4, rw5, rb5, out);
}